// Round 8
// baseline (178.750 us; speedup 1.0000x reference)
//
#include <hip/hip_runtime.h>

#define NT     25600   // B*S tokens
#define WCH    16      // chars per token
#define DIM    64
#define VOCAB  96
#define HID    128
#define KP     416     // GEMM K: 52 slot8-groups * 8
#define TOKB   64      // tokens per block in fused kernel
// T2 layout: [13 octets][14 slots][96 chars][8 halves]; slice = 10752 halves

typedef __attribute__((ext_vector_type(8))) _Float16 h8;
typedef __attribute__((ext_vector_type(4))) float f32x4;
typedef __attribute__((ext_vector_type(4))) int i32x4;

__device__ __forceinline__ float tanh_fast(float m) {
  float t = fminf(fmaxf(m, -9.f), 9.f);
  float e = __builtin_amdgcn_exp2f(t * 2.885390082f);  // e^{2t}
  return 1.f - 2.f * __builtin_amdgcn_rcpf(e + 1.f);
}

// ================= prep kernel: 3 roles by blockIdx =================
// A [0,168):   T2 build; slot = b/12, char-group = b%12 (8 chars)
// B [168,232): wprojP[128][416] f16 in slot8-major k order
// C [232,488): hw = tw0|gw0|tw1|gw1 as f16, 128*128 each
__global__ __launch_bounds__(256) void k_prep(
    const float* __restrict__ cv,
    const float* __restrict__ f2, const float* __restrict__ f3,
    const float* __restrict__ f4, const float* __restrict__ f5,
    const float* __restrict__ wproj,
    const float* __restrict__ tw0, const float* __restrict__ gw0,
    const float* __restrict__ tw1, const float* __restrict__ gw1,
    _Float16* __restrict__ T2, _Float16* __restrict__ wprojP,
    _Float16* __restrict__ hw) {
  __shared__ float fS[100 * 65];
  __shared__ float cvS[8 * 65];
  const int tid = threadIdx.x;
  const int b = blockIdx.x;

  if (b < 168) {
    const int slot = b / 12, cg = b - slot * 12;
    int wi, j;
    if (slot < 2)      { wi = 0; j = slot; }
    else if (slot < 5) { wi = 1; j = slot - 2; }
    else if (slot < 9) { wi = 2; j = slot - 5; }
    else               { wi = 3; j = slot - 9; }
    const float* filt = (wi == 0) ? f2 : (wi == 1) ? f3 : (wi == 2) ? f4 : f5;
    const int rowlen = (wi + 2) * DIM;
    for (int idx = tid; idx < 100 * DIM; idx += 256) {
      int f = idx >> 6, d = idx & 63;
      fS[f * 65 + d] = filt[f * rowlen + j * DIM + d];
    }
    for (int idx = tid; idx < 8 * DIM; idx += 256) {
      int c = idx >> 6, d = idx & 63;
      cvS[c * 65 + d] = cv[(cg * 8 + c) * DIM + d];
    }
    __syncthreads();
    for (int idx = tid; idx < 8 * 104; idx += 256) {
      int cl = idx / 104, f = idx - cl * 104;
      float s = 0.f;
      if (f < 100) {
#pragma unroll 8
        for (int d = 0; d < DIM; ++d) s += cvS[cl * 65 + d] * fS[f * 65 + d];
      }
      T2[((size_t)(f >> 3) * 14 + slot) * 768 + (cg * 8 + cl) * 8 + (f & 7)] =
          (_Float16)s;
    }
  } else if (b < 232) {
    const int n = (b - 168) * 2 + (tid >> 7);
    for (int k = tid & 127; k < KP; k += 128) {
      int s8 = k >> 3;
      int wi = s8 / 13;
      int fl = (s8 - wi * 13) * 8 + (k & 7);
      wprojP[n * KP + k] =
          (fl < 100) ? (_Float16)wproj[n * 400 + wi * 100 + fl] : (_Float16)0.f;
    }
  } else {
    const int idx = (b - 232) * 256 + tid;   // < 65536
    const int which = idx >> 14, r = idx & 16383;
    const float* src = (which == 0) ? tw0 : (which == 1) ? gw0
                     : (which == 2) ? tw1 : gw1;
    hw[idx] = (_Float16)src[r];
  }
}

// ---------------- conv for one (token=lane, window, octet) from LDS slice ----------------
// Ts: [14 slots][96 chars][8 halves]; ch[] entries pre-scaled by 8.
template<int WI>
__device__ __forceinline__ void conv_oct(const _Float16* __restrict__ Ts,
                                         const int* __restrict__ ch,
                                         _Float16* __restrict__ convA,
                                         int lane, int ls8) {
  constexpr int W = WI + 2, L = 15 - WI;
  constexpr int SB = (WI == 0) ? 0 : (WI == 1) ? 2 : (WI == 2) ? 5 : 9;
  h8 m;
  {
    h8 s = *(const h8*)(Ts + SB * 768 + ch[0]);
#pragma unroll
    for (int j = 1; j < W; ++j) s += *(const h8*)(Ts + (SB + j) * 768 + ch[j]);
    m = s;
  }
#pragma unroll
  for (int l = 1; l < L; ++l) {
    h8 s = *(const h8*)(Ts + SB * 768 + ch[l]);
#pragma unroll
    for (int j = 1; j < W; ++j) s += *(const h8*)(Ts + (SB + j) * 768 + ch[l + j]);
    m = __builtin_elementwise_max(m, s);
  }
  h8 r;
#pragma unroll
  for (int i = 0; i < 8; ++i) r[i] = (_Float16)tanh_fast((float)m[i]);
  *(h8*)(convA + (ls8 * 64 + lane) * 8) = r;
}

// ================= fused conv (LDS-staged T, 2 K-passes) + MFMA head =================
// 64 tokens/block, 256 threads (4 waves); token = lane, window rotates per wave.
// A-frag (16x16x32 f16): A[m=lane&15][k=quad*8+j]; D: row=quad*4+reg, col=lane&15.
__global__ __launch_bounds__(256) void k_fused(
    const int* __restrict__ chars,
    const _Float16* __restrict__ T2,
    const _Float16* __restrict__ wprojP,
    const _Float16* __restrict__ hw,
    const float* __restrict__ tb0, const float* __restrict__ tb1,
    const float* __restrict__ gb0, const float* __restrict__ gb1,
    float* __restrict__ out) {
  __shared__ __align__(16) char lds[50176];
  _Float16* Ts    = (_Float16*)lds;            // 21,504 B slice
  _Float16* xA    = (_Float16*)lds;            // 16,384 B (alias, post-conv)
  _Float16* convA = (_Float16*)(lds + 21504);  // 28,672 B (28 groups x 64 x 8)

  const int tid = threadIdx.x;
  const int wave = tid >> 6, lane = tid & 63;
  const int m16 = lane & 15, quad = lane >> 4;
  const int tok0 = blockIdx.x * TOKB;
  const f32x4 zero = {0.f, 0.f, 0.f, 0.f};

  // per-thread chars for token = lane (all waves identical), pre-scaled by 8
  int ch[WCH];
  {
    const i32x4* cp = (const i32x4*)(chars + (size_t)(tok0 + lane) * WCH);
#pragma unroll
    for (int q = 0; q < 4; ++q) {
      i32x4 v = cp[q];
#pragma unroll
      for (int i = 0; i < 4; ++i) ch[q * 4 + i] = v[i] * 8;
    }
  }

  const int hcA = wave * 16 + m16;
  const int hcB = hcA + 64;
  f32x4 xp[4][2];
#pragma unroll
  for (int mt = 0; mt < 4; ++mt) { xp[mt][0] = zero; xp[mt][1] = zero; }

  // ---- conv + projection in 2 K-passes (octets 0..6 then 7..12) ----
#pragma unroll
  for (int pass = 0; pass < 2; ++pass) {
    const int obeg = pass ? 7 : 0, oend = pass ? 13 : 7;
    for (int o = obeg; o < oend; ++o) {
      __syncthreads();   // prior MFMA convA reads + prior round Ts reads done
      const _Float16* src = T2 + (size_t)o * 10752;
      for (int r = tid; r < 1344; r += 256)
        *(h8*)(Ts + r * 8) = *(const h8*)(src + r * 8);
      __syncthreads();
      const int win = (wave + o) & 3;
      const int ls8 = pass ? (win * 6 + o - 7) : (win * 7 + o);
      switch (win) {
        case 0: conv_oct<0>(Ts, ch, convA, lane, ls8); break;
        case 1: conv_oct<1>(Ts, ch, convA, lane, ls8); break;
        case 2: conv_oct<2>(Ts, ch, convA, lane, ls8); break;
        default: conv_oct<3>(Ts, ch, convA, lane, ls8); break;
      }
    }
    __syncthreads();
    const int ng = pass ? 6 : 7;         // groups this pass: 24 / 28
    const int per = pass ? 6 : 7;
    const int ob = pass ? 7 : 0;
    for (int ks = 0; ks < ng; ++ks) {
      const int g = ks * 4 + quad;
      const int win = g / per;
      const int s8 = win * 13 + (g - win * per) + ob;
      h8 b0 = *(const h8*)(wprojP + (size_t)hcA * KP + s8 * 8);
      h8 b1 = *(const h8*)(wprojP + (size_t)hcB * KP + s8 * 8);
#pragma unroll
      for (int mt = 0; mt < 4; ++mt) {
        h8 a = *(const h8*)(convA + (g * 64 + mt * 16 + m16) * 8);
        xp[mt][0] = __builtin_amdgcn_mfma_f32_16x16x32_f16(a, b0, xp[mt][0], 0, 0, 0);
        xp[mt][1] = __builtin_amdgcn_mfma_f32_16x16x32_f16(a, b1, xp[mt][1], 0, 0, 0);
      }
    }
  }

  // write x0 (f16) into xA [16 kslots][64 rows][8] (aliases Ts — safe post-barrier)
  __syncthreads();
#pragma unroll
  for (int mt = 0; mt < 4; ++mt)
#pragma unroll
    for (int nt = 0; nt < 2; ++nt) {
      int col = nt * 64 + hcA;
#pragma unroll
      for (int r = 0; r < 4; ++r)
        xA[(col >> 3) * 512 + (mt * 16 + quad * 4 + r) * 8 + (col & 7)] =
            (_Float16)xp[mt][nt][r];
    }
  __syncthreads();

  // ---- highway layers ----
#pragma unroll
  for (int layer = 0; layer < 2; ++layer) {
    const _Float16* tw = hw + (layer ? 2 : 0) * HID * HID;
    const _Float16* gw = hw + (layer ? 3 : 1) * HID * HID;
    const float* tbv = layer ? tb1 : tb0;
    const float* gbv = layer ? gb1 : gb0;
    float btA = tbv[hcA], bgA = gbv[hcA];
    float btB = tbv[hcB], bgB = gbv[hcB];

    f32x4 at[4][2], ag[4][2];
#pragma unroll
    for (int mt = 0; mt < 4; ++mt) {
      at[mt][0] = zero; at[mt][1] = zero;
      ag[mt][0] = zero; ag[mt][1] = zero;
    }
#pragma unroll
    for (int ks = 0; ks < 4; ++ks) {
      const int ko = ks * 32 + quad * 8;
      h8 bt0 = *(const h8*)(tw + (size_t)hcA * HID + ko);
      h8 bt1 = *(const h8*)(tw + (size_t)hcB * HID + ko);
      h8 bg0 = *(const h8*)(gw + (size_t)hcA * HID + ko);
      h8 bg1 = *(const h8*)(gw + (size_t)hcB * HID + ko);
#pragma unroll
      for (int mt = 0; mt < 4; ++mt) {
        h8 a = *(const h8*)(xA + (ks * 4 + quad) * 512 + (mt * 16 + m16) * 8);
        at[mt][0] = __builtin_amdgcn_mfma_f32_16x16x32_f16(a, bt0, at[mt][0], 0, 0, 0);
        at[mt][1] = __builtin_amdgcn_mfma_f32_16x16x32_f16(a, bt1, at[mt][1], 0, 0, 0);
        ag[mt][0] = __builtin_amdgcn_mfma_f32_16x16x32_f16(a, bg0, ag[mt][0], 0, 0, 0);
        ag[mt][1] = __builtin_amdgcn_mfma_f32_16x16x32_f16(a, bg1, ag[mt][1], 0, 0, 0);
      }
    }
    __syncthreads();   // xA reads done before overwrite

#pragma unroll
    for (int mt = 0; mt < 4; ++mt)
#pragma unroll
      for (int nt = 0; nt < 2; ++nt) {
        float bt = nt ? btB : btA, bg = nt ? bgB : bgA;
        int col = nt * 64 + hcA;
#pragma unroll
        for (int r = 0; r < 4; ++r) {
          float g = 1.f / (1.f + __builtin_amdgcn_exp2f(
                               -(ag[mt][nt][r] + bg) * 1.442695041f));
          float tt = fmaxf(at[mt][nt][r] + bt, 0.f);
          float xn = g * tt + (1.f - g) * xp[mt][nt][r];
          xp[mt][nt][r] = xn;
          int row = mt * 16 + quad * 4 + r;
          if (layer == 0)
            xA[(col >> 3) * 512 + row * 8 + (col & 7)] = (_Float16)xn;
          else
            out[(size_t)(tok0 + row) * HID + col] = xn;
        }
      }
    if (layer == 0) __syncthreads();
  }
}

extern "C" void kernel_launch(void* const* d_in, const int* in_sizes, int n_in,
                              void* d_out, int out_size, void* d_ws, size_t ws_size,
                              hipStream_t stream) {
  (void)in_sizes; (void)n_in; (void)out_size; (void)ws_size;
  const int* chars = (const int*)d_in[0];
  const float* cv  = (const float*)d_in[1];
  const float* f2  = (const float*)d_in[2];
  const float* f3  = (const float*)d_in[3];
  const float* f4  = (const float*)d_in[4];
  const float* f5  = (const float*)d_in[5];
  const float* wpj = (const float*)d_in[6];
  const float* tw0 = (const float*)d_in[7];
  const float* tb0 = (const float*)d_in[8];
  const float* tw1 = (const float*)d_in[9];
  const float* tb1 = (const float*)d_in[10];
  const float* gw0 = (const float*)d_in[11];
  const float* gb0 = (const float*)d_in[12];
  const float* gw1 = (const float*)d_in[13];
  const float* gb1 = (const float*)d_in[14];
  float* out = (float*)d_out;

  char* ws = (char*)d_ws;
  _Float16* T2     = (_Float16*)ws;                       // 13*14*96*8*2 = 279,552 B
  _Float16* wprojP = (_Float16*)(ws + 279552);            // 106,496 B
  _Float16* hw     = (_Float16*)(ws + 279552 + 106496);   // 131,072 B (total 517,120 B)

  k_prep<<<488, 256, 0, stream>>>(cv, f2, f3, f4, f5, wpj, tw0, gw0, tw1, gw1,
                                  T2, wprojP, hw);
  k_fused<<<NT / TOKB, 256, 0, stream>>>(chars, T2, wprojP, hw,
                                         tb0, tb1, gb0, gb1, out);
}